// Round 1
// baseline (673.973 us; speedup 1.0000x reference)
//
#include <hip/hip_runtime.h>
#include <stdint.h>

#define N_KERNELS 10000
#define NCHUNK 56            // >= sum_g ceil(size_g/256) worst case
#define RNG_STEPS 10         // 1024 threads * 10 next64 = 20480 u32 draws >= 20000
#define CH_ALLOC 1312        // shorts per (copy,channel); mult of 4 (8B granules)
#define PP_STRIDE (3 * CH_ALLOC)
#define NPHASE 4

typedef unsigned __int128 u128;
typedef __attribute__((ext_vector_type(4)))  short short4v;
typedef __attribute__((ext_vector_type(8)))  short short8;
typedef __attribute__((ext_vector_type(16))) float floatx16;

// ---------------------------------------------------------------------------
// Setup (R12 rewrite): one 1024-thread block.
//  Phase A: PCG64 draws (verified algorithm, new decomposition: 1024 thr x 10
//           next64, same global sequence positions) -> k/d bytes in LDS.
//  Phase B: per-wave group histogram via ballots (NO atomics).
//  Phase C: wave 0: group offsets (shfl scan) + per-(wave,group) scatter base.
//  Phase D: scatter via ballot-rank (NO atomics). Order within a group is
//           irrelevant for correctness (outputs addressed by kernel index).
//  Phase E: thread 0 builds the 56-entry sched table (unchanged semantics).
// Replaces ~20k serialized same-address LDS atomics (~70us on one CU).
// ---------------------------------------------------------------------------
__global__ __launch_bounds__(1024)
void setup_kernel(int* __restrict__ list, int* __restrict__ sched) {
    const u128 MULT = (((u128)0x2360ED051FC65DA4ULL) << 64) | 0x4385DF649FCCF645ULL;
    const int tid  = threadIdx.x;
    const int lane = tid & 63;
    const int wave = tid >> 6;

    __shared__ uint8_t kb[10000];
    __shared__ uint8_t db[10000];
    __shared__ int wcnt[16 * 16];    // [wave][group] counts
    __shared__ int rb[16 * 16];      // [wave][group] scatter cursor
    __shared__ int cntS[16], offS[16];

    // ---- seeding (identical for all threads; verified vs numpy) -----------
    uint32_t hc = 0x43b0d7e5u;                    // INIT_A
    auto hashmix = [&hc](uint32_t v) -> uint32_t {
        v ^= hc; hc *= 0x931e8875u;               // MULT_A
        v *= hc; v ^= v >> 16; return v;
    };
    uint32_t pool[4];
    pool[0] = hashmix(0u);
    pool[1] = hashmix(0u);
    pool[2] = hashmix(0u);
    pool[3] = hashmix(0u);
    for (int s = 0; s < 4; s++)
        for (int dd = 0; dd < 4; dd++)
            if (s != dd) {
                uint32_t hv = hashmix(pool[s]);
                uint32_t rr = 0xca01f9ddu * pool[dd] - 0x4973f715u * hv;
                rr ^= rr >> 16;
                pool[dd] = rr;
            }
    uint32_t st[8];
    uint32_t hcb = 0x8b51f9ddu;                   // INIT_B
    for (int i = 0; i < 8; i++) {
        uint32_t dv = pool[i & 3];
        dv ^= hcb; hcb *= 0x58f38dedu;            // MULT_B
        dv *= hcb; dv ^= dv >> 16;
        st[i] = dv;
    }
    uint64_t w0 = (uint64_t)st[0] | ((uint64_t)st[1] << 32);
    uint64_t w1 = (uint64_t)st[2] | ((uint64_t)st[3] << 32);
    uint64_t w2 = (uint64_t)st[4] | ((uint64_t)st[5] << 32);
    uint64_t w3 = (uint64_t)st[6] | ((uint64_t)st[7] << 32);
    u128 initstate = (((u128)w0) << 64) | w1;
    u128 initseq   = (((u128)w2) << 64) | w3;

    u128 inc   = (initseq << 1) | 1;
    u128 state = 0;
    state = state * MULT + inc;
    state += initstate;
    state = state * MULT + inc;

    // ---- skipahead to this thread's slice ---------------------------------
    u128 Ae = 1, Ce = 0, Ab = MULT, Cb = inc;
    unsigned e = (unsigned)(tid * RNG_STEPS);
    while (e) {
        if (e & 1u) { Ae = Ab * Ae; Ce = Ab * Ce + Cb; }
        Cb = Ab * Cb + Cb;
        Ab = Ab * Ab;
        e >>= 1;
    }
    u128 s = Ae * state + Ce;

    int base = tid * (2 * RNG_STEPS);
    for (int t = 0; t < RNG_STEPS; t++) {
        s = s * MULT + inc;
        uint64_t hi = (uint64_t)(s >> 64), lo = (uint64_t)s;
        unsigned rot = (unsigned)(hi >> 58);
        uint64_t v = hi ^ lo;
        uint64_t o = (v >> rot) | (v << ((64u - rot) & 63u));
        uint32_t d0 = (uint32_t)o;
        uint32_t d1 = (uint32_t)(o >> 32);
        int i0 = base + 2 * t;
        if (i0 < 10000)       kb[i0] = (uint8_t)(((uint64_t)d0 * 3u) >> 32);
        else if (i0 < 20000)  db[i0 - 10000] = (uint8_t)(((uint64_t)d0 * 5u) >> 32);
        int i1 = i0 + 1;
        if (i1 < 10000)       kb[i1] = (uint8_t)(((uint64_t)d1 * 3u) >> 32);
        else if (i1 < 20000)  db[i1 - 10000] = (uint8_t)(((uint64_t)d1 * 5u) >> 32);
    }

    __syncthreads();

    // ---- Phase B: per-wave histogram via ballots --------------------------
    int cw = 0;                                   // lane g accumulates group g
    for (int r = 0; r < 10; ++r) {
        int i = r * 1024 + tid;
        int gid = 15;                             // dummy group for tail
        if (i < 10000) gid = (int)kb[i] * 5 + (int)db[i];
        #pragma unroll
        for (int g = 0; g < 15; ++g) {
            unsigned long long m = __ballot(gid == g);
            if (lane == g) cw += (int)__popcll(m);
        }
    }
    if (lane < 16) wcnt[wave * 16 + lane] = cw;   // lane 15 writes 0
    __syncthreads();

    // ---- Phase C: offsets + per-wave scatter bases (wave 0) ---------------
    if (wave == 0) {
        int tot = 0;
        if (lane < 16)
            for (int w2 = 0; w2 < 16; ++w2) tot += wcnt[w2 * 16 + lane];
        int incl = tot;
        #pragma unroll
        for (int d2 = 1; d2 < 16; d2 <<= 1) {
            int up = __shfl_up(incl, d2);
            if (lane >= d2) incl += up;           // lanes >=16 garbage, unused
        }
        int off = incl - tot;                     // exclusive prefix over groups
        if (lane < 16) {
            cntS[lane] = tot;
            offS[lane] = off;
            int acc = off;
            for (int w2 = 0; w2 < 16; ++w2) {
                rb[w2 * 16 + lane] = acc;
                acc += wcnt[w2 * 16 + lane];
            }
        }
    }
    __syncthreads();

    // ---- Phase D: scatter via ballot rank ---------------------------------
    for (int r = 0; r < 10; ++r) {
        int i = r * 1024 + tid;
        int gid = 15;
        if (i < 10000) gid = (int)kb[i] * 5 + (int)db[i];
        unsigned long long mym = 0; int cg = 0;
        #pragma unroll
        for (int g = 0; g < 15; ++g) {
            unsigned long long m = __ballot(gid == g);
            if (gid == g) mym = m;
            if (lane == g) cg = (int)__popcll(m);
        }
        int bpos = 0;
        if (gid < 15) bpos = rb[wave * 16 + gid];
        __syncthreads();                          // all reads before cursor bump
        if (lane < 15 && cg) rb[wave * 16 + lane] += cg;
        if (gid < 15) {
            int pos = bpos + (int)__popcll(mym & ((1ull << lane) - 1ull));
            list[pos] = i;
        }
        __syncthreads();
    }

    // ---- Phase E: sched table ---------------------------------------------
    if (tid == 0) {
        const int kv[3] = {7, 9, 11};
        int ci = 0;
        for (int g = 0; g < 15; ++g) {
            int sz = cntS[g];
            for (int s2 = 0; s2 < sz; s2 += 256) {
                int4 e2;
                e2.x = kv[g / 5];
                e2.y = g % 5;
                e2.z = offS[g] + s2;
                e2.w = (sz - s2 < 256) ? (sz - s2) : 256;
                reinterpret_cast<int4*>(sched)[ci++] = e2;
            }
        }
        for (; ci < NCHUNK; ci++) {
            int4 e2; e2.x = 0; e2.y = 0; e2.z = 0; e2.w = 0;
            reinterpret_cast<int4*>(sched)[ci] = e2;
        }
    }
}

// ---------------------------------------------------------------------------
// Main: bf16 MFMA Toeplitz GEMM (R6 coverage structure, verified correct).
// R11: manual x2 unroll of the position loop, two persistent frag sets.
// R12: __launch_bounds__ 4->5 — LDS 31744B allows 5 blocks/CU (158.7KB of
// 160KB); VGPR=64 stays under the 96-cap, so no codegen change, only
// residency (+tail quantization: 2.8 dispatch waves of 1280 vs 3.5 of 1024).
// ---------------------------------------------------------------------------
__device__ __forceinline__ uint16_t f32_to_bf16(float v) {
    uint32_t u = __builtin_bit_cast(uint32_t, v);
    return (uint16_t)((u + 0x7FFFu + ((u >> 16) & 1u)) >> 16);
}

__device__ __forceinline__ void stat16(const floatx16& C, float& mx, int& cnt) {
    float g0 = fmaxf(fmaxf(C[0],  C[1]),  C[2]);
    float g1 = fmaxf(fmaxf(C[3],  C[4]),  C[5]);
    float g2 = fmaxf(fmaxf(C[6],  C[7]),  C[8]);
    float g3 = fmaxf(fmaxf(C[9],  C[10]), C[11]);
    float g4 = fmaxf(fmaxf(C[12], C[13]), C[14]);
    float h0 = fmaxf(fmaxf(g0, g1), g2);
    float h1 = fmaxf(fmaxf(g3, g4), C[15]);
    mx = fmaxf(mx, fmaxf(h0, h1));
    uint32_t mA = 0, mB = 0;
    #pragma unroll
    for (int i = 0; i < 16; i += 2) {
        mA = (mA << 1) | (__builtin_bit_cast(uint32_t, C[i])     >> 31);
        mB = (mB << 1) | (__builtin_bit_cast(uint32_t, C[i + 1]) >> 31);
    }
    cnt += __popc(mA) + __popc(mB);
}

__device__ __forceinline__ int swz_g(int g) { return g ^ ((g >> 4) & 3); }

template <int K, int D>
__device__ __forceinline__ void body(const float* __restrict__ x,
                                     const float* __restrict__ wgt,
                                     const float* __restrict__ bias,
                                     const int* __restrict__ list,
                                     int lstart, int valid,
                                     float* __restrict__ out,
                                     short* __restrict__ xs,   // [4][3][CH_ALLOC]
                                     int b) {
    constexpr int H   = (K - 1) / 2;
    constexpr int Q   = 1024 / D;
    constexpr int S   = Q + 16;                    // residue slot stride (gap 16)
    constexpr int RS  = (D <= 4) ? 8 : (D == 8 ? 4 : 2);   // row stride (positions)
    constexpr int NIT = 32;                        // total iterations (all D), even

    const int tid   = threadIdx.x;
    const int lane  = tid & 63;
    const int wave  = tid >> 6;
    const int jbase = (lane >> 5) * 8;             // k-half offset (0 or 8 shorts)
    const int m31   = lane & 31;                   // A row / C-D column index

    // ---- stage: 4 phase-copies, bank-swizzled at 8B-granule level ---------
    for (int idx = tid; idx < 3 * (CH_ALLOC + NPHASE); idx += 256) {
        int c = idx / (CH_ALLOC + NPHASE);
        int P = idx - c * (CH_ALLOC + NPHASE);
        float v = 0.f;
        int y = P - 8;
        if (y >= 0) {
            int r = y / S;
            int q = y - r * S;
            if (r < D && q < Q) v = x[((size_t)b * 3 + c) * 1024 + r + D * q];
        }
        short hv = (short)f32_to_bf16(v);
        #pragma unroll
        for (int pp = 0; pp < NPHASE; ++pp) {
            int ee = P - pp;
            if (ee >= 0 && ee < CH_ALLOC) {
                int phys = (swz_g(ee >> 2) << 2) | (ee & 3);
                xs[pp * PP_STRIDE + c * CH_ALLOC + phys] = hv;
            }
        }
    }

    // ---- per-lane B fragments (single bf16 weights), overlap staging ------
    int i0 = wave * 64 + m31;
    int i1 = i0 + 32;
    int n0 = list[lstart + (i0 < valid ? i0 : valid - 1)];
    int n1 = list[lstart + (i1 < valid ? i1 : valid - 1)];
    short8 whi[2][3];
    #pragma unroll
    for (int t2 = 0; t2 < 2; ++t2) {
        int n = t2 ? n1 : n0;
        #pragma unroll
        for (int c = 0; c < 3; ++c) {
            #pragma unroll
            for (int u = 0; u < 8; ++u) {
                int j = jbase + u;
                float wv = (j < 11) ? wgt[n * 33 + c * 11 + j] : 0.f;
                whi[t2][c][u] = (short)f32_to_bf16(wv);
            }
        }
    }
    float bv0 = bias[n0], bv1 = bias[n1];

    floatx16 BT0, BT1;                             // persistent bias seed tiles
    #pragma unroll
    for (int i = 0; i < 16; ++i) { BT0[i] = bv0; BT1[i] = bv1; }

    __syncthreads();

    // ---- window-start index for flattened iteration it --------------------
    auto calcF = [&](int it) -> int {
        int ri, p;
        if (D <= 4)      { ri = it >> 3; p = it & 7; }
        else if (D == 8) { ri = it >> 2; p = it & 3; }
        else             { ri = it >> 1; p = it & 1; }
        int q0;
        if (D == 1)      q0 = 8 + ri * 256;
        else if (D == 2) q0 = 8 + (ri >> 1) * S + (ri & 1) * 256;
        else             q0 = 8 + ri * S;
        return q0 + p - H + RS * m31;
    };
    // swizzled 2x b64 frag load (frag = logical shorts [(F&~3)+jbase, +8))
    auto loadfrag = [&](int F, short8& A0, short8& A1, short8& A2) {
        int g0 = (F >> 2) + (jbase >> 2);
        int s0 = swz_g(g0) << 2;
        int s1 = swz_g(g0 + 1) << 2;
        const short* bp = xs + (F & 3) * PP_STRIDE;
        short4v l0 = *reinterpret_cast<const short4v*>(bp + s0);
        short4v h0 = *reinterpret_cast<const short4v*>(bp + s1);
        short4v l1 = *reinterpret_cast<const short4v*>(bp + CH_ALLOC + s0);
        short4v h1 = *reinterpret_cast<const short4v*>(bp + CH_ALLOC + s1);
        short4v l2 = *reinterpret_cast<const short4v*>(bp + 2 * CH_ALLOC + s0);
        short4v h2 = *reinterpret_cast<const short4v*>(bp + 2 * CH_ALLOC + s1);
        A0 = __builtin_shufflevector(l0, h0, 0, 1, 2, 3, 4, 5, 6, 7);
        A1 = __builtin_shufflevector(l1, h1, 0, 1, 2, 3, 4, 5, 6, 7);
        A2 = __builtin_shufflevector(l2, h2, 0, 1, 2, 3, 4, 5, 6, 7);
    };

    // ---- main loop: manual x2 unroll, two persistent frag sets ------------
    float mx0 = -3.402823466e38f, mx1 = -3.402823466e38f;
    int cnt0 = 0, cnt1 = 0;                        // negative counts

    short8 a0, a1, a2, b0, b1, b2;
    loadfrag(calcF(0), a0, a1, a2);
    loadfrag(calcF(1), b0, b1, b2);

    #pragma unroll 1
    for (int it = 0; it < NIT; it += 2) {
        int itA = (it + 2 < NIT) ? it + 2 : NIT - 1;   // clamp (redundant reload)
        int itB = (it + 3 < NIT) ? it + 3 : NIT - 1;

        // ---- iteration it (frag set A) ----
        floatx16 C0, C1;
        C0 = __builtin_amdgcn_mfma_f32_32x32x16_bf16(a0, whi[0][0], BT0, 0, 0, 0);
        C0 = __builtin_amdgcn_mfma_f32_32x32x16_bf16(a1, whi[0][1], C0, 0, 0, 0);
        C0 = __builtin_amdgcn_mfma_f32_32x32x16_bf16(a2, whi[0][2], C0, 0, 0, 0);
        C1 = __builtin_amdgcn_mfma_f32_32x32x16_bf16(a0, whi[1][0], BT1, 0, 0, 0);
        C1 = __builtin_amdgcn_mfma_f32_32x32x16_bf16(a1, whi[1][1], C1, 0, 0, 0);
        C1 = __builtin_amdgcn_mfma_f32_32x32x16_bf16(a2, whi[1][2], C1, 0, 0, 0);
        loadfrag(calcF(itA), a0, a1, a2);           // set A free -> prefetch it+2
        stat16(C0, mx0, cnt0);
        stat16(C1, mx1, cnt1);

        // ---- iteration it+1 (frag set B) ----
        floatx16 D0, D1;
        D0 = __builtin_amdgcn_mfma_f32_32x32x16_bf16(b0, whi[0][0], BT0, 0, 0, 0);
        D0 = __builtin_amdgcn_mfma_f32_32x32x16_bf16(b1, whi[0][1], D0, 0, 0, 0);
        D0 = __builtin_amdgcn_mfma_f32_32x32x16_bf16(b2, whi[0][2], D0, 0, 0, 0);
        D1 = __builtin_amdgcn_mfma_f32_32x32x16_bf16(b0, whi[1][0], BT1, 0, 0, 0);
        D1 = __builtin_amdgcn_mfma_f32_32x32x16_bf16(b1, whi[1][1], D1, 0, 0, 0);
        D1 = __builtin_amdgcn_mfma_f32_32x32x16_bf16(b2, whi[1][2], D1, 0, 0, 0);
        loadfrag(calcF(itB), b0, b1, b2);           // set B free -> prefetch it+3
        stat16(D0, mx0, cnt0);
        stat16(D1, mx1, cnt1);
    }

    // ---- merge complementary row halves across the (L, L^32) lane pair ----
    mx0  = fmaxf(mx0, __shfl_xor(mx0, 32));
    mx1  = fmaxf(mx1, __shfl_xor(mx1, 32));
    cnt0 += __shfl_xor(cnt0, 32);
    cnt1 += __shfl_xor(cnt1, 32);

    if (lane < 32) {
        float2* ob = reinterpret_cast<float2*>(out + (size_t)b * (2 * N_KERNELS));
        ob[n0] = make_float2(mx0, (float)(1024 - cnt0) * (1.0f / 1024.0f));
        ob[n1] = make_float2(mx1, (float)(1024 - cnt1) * (1.0f / 1024.0f));
    }
}

__global__ __launch_bounds__(256, 5)
void rocket_main(const float* __restrict__ x, const float* __restrict__ wgt,
                 const float* __restrict__ bias, const int* __restrict__ list,
                 const int* __restrict__ sched, float* __restrict__ out) {
    __shared__ __align__(16) short xs[NPHASE * PP_STRIDE];   // 31.5 KB
    int4 e = reinterpret_cast<const int4*>(sched)[blockIdx.x];
    if (e.w == 0) return;                                // dead chunk — uniform exit
    int b = blockIdx.y;
    int kc = e.x, ld2 = e.y, lstart = e.z, valid = e.w;
    switch (kc * 8 + ld2) {
        case 7*8+0:  body<7, 1 >(x, wgt, bias, list, lstart, valid, out, xs, b); break;
        case 7*8+1:  body<7, 2 >(x, wgt, bias, list, lstart, valid, out, xs, b); break;
        case 7*8+2:  body<7, 4 >(x, wgt, bias, list, lstart, valid, out, xs, b); break;
        case 7*8+3:  body<7, 8 >(x, wgt, bias, list, lstart, valid, out, xs, b); break;
        case 7*8+4:  body<7, 16>(x, wgt, bias, list, lstart, valid, out, xs, b); break;
        case 9*8+0:  body<9, 1 >(x, wgt, bias, list, lstart, valid, out, xs, b); break;
        case 9*8+1:  body<9, 2 >(x, wgt, bias, list, lstart, valid, out, xs, b); break;
        case 9*8+2:  body<9, 4 >(x, wgt, bias, list, lstart, valid, out, xs, b); break;
        case 9*8+3:  body<9, 8 >(x, wgt, bias, list, lstart, valid, out, xs, b); break;
        case 9*8+4:  body<9, 16>(x, wgt, bias, list, lstart, valid, out, xs, b); break;
        case 11*8+0: body<11,1 >(x, wgt, bias, list, lstart, valid, out, xs, b); break;
        case 11*8+1: body<11,2 >(x, wgt, bias, list, lstart, valid, out, xs, b); break;
        case 11*8+2: body<11,4 >(x, wgt, bias, list, lstart, valid, out, xs, b); break;
        case 11*8+3: body<11,8 >(x, wgt, bias, list, lstart, valid, out, xs, b); break;
        default:     body<11,16>(x, wgt, bias, list, lstart, valid, out, xs, b); break;
    }
}

extern "C" void kernel_launch(void* const* d_in, const int* in_sizes, int n_in,
                              void* d_out, int out_size, void* d_ws, size_t ws_size,
                              hipStream_t stream) {
    const float* x   = (const float*)d_in[0];
    const float* w   = (const float*)d_in[1];
    const float* b   = (const float*)d_in[2];
    float* out = (float*)d_out;

    int* wsi  = (int*)d_ws;
    int* list = wsi;            // 10000 ints
    int* schd = wsi + 10240;    // NCHUNK*4 ints (byte offset 40960, 16B aligned)

    hipLaunchKernelGGL(setup_kernel, dim3(1), dim3(1024), 0, stream,
                       list, schd);
    hipLaunchKernelGGL(rocket_main,  dim3(NCHUNK, 64), dim3(256), 0, stream,
                       x, w, b, list, schd, out);
}

// Round 2
// 186.427 us; speedup vs baseline: 3.6152x; 3.6152x over previous
//
#include <hip/hip_runtime.h>
#include <stdint.h>

#define N_KERNELS 10000
#define NCHUNK 56            // >= sum_g ceil(size_g/256) worst case
#define CH_ALLOC 1312        // shorts per (copy,channel); mult of 4 (8B granules)
#define PP_STRIDE (3 * CH_ALLOC)
#define NPHASE 4

typedef unsigned __int128 u128;
typedef __attribute__((ext_vector_type(4)))  short short4v;
typedef __attribute__((ext_vector_type(8)))  short short8;
typedef __attribute__((ext_vector_type(16))) float floatx16;

// ---------------------------------------------------------------------------
// R13: setup moved to HOST. The k/d draws come from numpy default_rng(0) —
// fixed, input-independent. The PCG64/SeedSequence algorithm below is the
// verbatim (verified R1-R10) device algorithm run sequentially on the CPU at
// first kernel_launch; list/sched are memcpy'd (41.8 KB) onto the stream.
// Removes the serialized single-block setup dispatch (~50-80us) entirely.
// ---------------------------------------------------------------------------
namespace {
struct SetupTables {
    int buf[10240 + 4 * NCHUNK];   // [0..9999]=list, [10240..]=sched (int4 x56)
    SetupTables() {
        const u128 MULT = (((u128)0x2360ED051FC65DA4ULL) << 64) | 0x4385DF649FCCF645ULL;

        // ---- SeedSequence(0) -> PCG64 state (verified vs numpy) ----------
        uint32_t hc = 0x43b0d7e5u;                    // INIT_A
        auto hashmix = [&hc](uint32_t v) -> uint32_t {
            v ^= hc; hc *= 0x931e8875u;               // MULT_A
            v *= hc; v ^= v >> 16; return v;
        };
        uint32_t pool[4];
        pool[0] = hashmix(0u);
        pool[1] = hashmix(0u);
        pool[2] = hashmix(0u);
        pool[3] = hashmix(0u);
        for (int s = 0; s < 4; s++)
            for (int dd = 0; dd < 4; dd++)
                if (s != dd) {
                    uint32_t hv = hashmix(pool[s]);
                    uint32_t rr = 0xca01f9ddu * pool[dd] - 0x4973f715u * hv;
                    rr ^= rr >> 16;
                    pool[dd] = rr;
                }
        uint32_t st[8];
        uint32_t hcb = 0x8b51f9ddu;                   // INIT_B
        for (int i = 0; i < 8; i++) {
            uint32_t dv = pool[i & 3];
            dv ^= hcb; hcb *= 0x58f38dedu;            // MULT_B
            dv *= hcb; dv ^= dv >> 16;
            st[i] = dv;
        }
        uint64_t w0 = (uint64_t)st[0] | ((uint64_t)st[1] << 32);
        uint64_t w1 = (uint64_t)st[2] | ((uint64_t)st[3] << 32);
        uint64_t w2 = (uint64_t)st[4] | ((uint64_t)st[5] << 32);
        uint64_t w3 = (uint64_t)st[6] | ((uint64_t)st[7] << 32);
        u128 initstate = (((u128)w0) << 64) | w1;
        u128 initseq   = (((u128)w2) << 64) | w3;

        u128 inc   = (initseq << 1) | 1;
        u128 state = 0;
        state = state * MULT + inc;
        state += initstate;
        state = state * MULT + inc;

        // ---- 10000 next64 -> 20000 u32 draws (low word first) ------------
        static uint8_t karr[10000], darr[10000];
        u128 s = state;
        for (int t = 0; t < 10000; ++t) {
            s = s * MULT + inc;
            uint64_t hi = (uint64_t)(s >> 64), lo = (uint64_t)s;
            unsigned rot = (unsigned)(hi >> 58);
            uint64_t v = hi ^ lo;
            uint64_t o = (v >> rot) | (v << ((64u - rot) & 63u));
            uint32_t d0 = (uint32_t)o;
            uint32_t d1 = (uint32_t)(o >> 32);
            int i0 = 2 * t, i1 = 2 * t + 1;
            if (i0 < 10000) karr[i0] = (uint8_t)(((uint64_t)d0 * 3u) >> 32);
            else            darr[i0 - 10000] = (uint8_t)(((uint64_t)d0 * 5u) >> 32);
            if (i1 < 10000) karr[i1] = (uint8_t)(((uint64_t)d1 * 3u) >> 32);
            else            darr[i1 - 10000] = (uint8_t)(((uint64_t)d1 * 5u) >> 32);
        }

        // ---- bucket by group g = k_idx*5 + d_idx (ascending order) -------
        int cnt[15] = {0}, off[15], cur[15];
        for (int i = 0; i < 10000; ++i) cnt[(int)karr[i] * 5 + (int)darr[i]]++;
        int o = 0;
        for (int g = 0; g < 15; ++g) { off[g] = o; cur[g] = o; o += cnt[g]; }
        for (int i = 0; i < 10000; ++i) {
            int g = (int)karr[i] * 5 + (int)darr[i];
            buf[cur[g]++] = i;
        }

        // ---- sched table (k, log2(d)-index, list_start, valid) -----------
        const int kv[3] = {7, 9, 11};
        int ci = 0;
        for (int g = 0; g < 15; ++g) {
            int sz = cnt[g];
            for (int s2 = 0; s2 < sz; s2 += 256) {
                int* e2 = &buf[10240 + 4 * ci];
                e2[0] = kv[g / 5];
                e2[1] = g % 5;
                e2[2] = off[g] + s2;
                e2[3] = (sz - s2 < 256) ? (sz - s2) : 256;
                ci++;
            }
        }
        for (; ci < NCHUNK; ci++) {
            int* e2 = &buf[10240 + 4 * ci];
            e2[0] = 0; e2[1] = 0; e2[2] = 0; e2[3] = 0;
        }
    }
};
} // namespace

// ---------------------------------------------------------------------------
// Main: bf16 MFMA Toeplitz GEMM (R6 coverage structure, verified correct).
// R11: manual x2 unroll of the position loop, two persistent frag sets.
// R12 POST-MORTEM: __launch_bounds__(256,5) capped VGPRs below the kernel's
// need (64 arch + acc) -> scratch spills (FETCH 5.4MB -> 1.2GB, 6x slowdown).
// KEEP (256,4): LDS would allow 5 blocks/CU but the register budget does not.
// ---------------------------------------------------------------------------
__device__ __forceinline__ uint16_t f32_to_bf16(float v) {
    uint32_t u = __builtin_bit_cast(uint32_t, v);
    return (uint16_t)((u + 0x7FFFu + ((u >> 16) & 1u)) >> 16);
}

__device__ __forceinline__ void stat16(const floatx16& C, float& mx, int& cnt) {
    float g0 = fmaxf(fmaxf(C[0],  C[1]),  C[2]);
    float g1 = fmaxf(fmaxf(C[3],  C[4]),  C[5]);
    float g2 = fmaxf(fmaxf(C[6],  C[7]),  C[8]);
    float g3 = fmaxf(fmaxf(C[9],  C[10]), C[11]);
    float g4 = fmaxf(fmaxf(C[12], C[13]), C[14]);
    float h0 = fmaxf(fmaxf(g0, g1), g2);
    float h1 = fmaxf(fmaxf(g3, g4), C[15]);
    mx = fmaxf(mx, fmaxf(h0, h1));
    uint32_t mA = 0, mB = 0;
    #pragma unroll
    for (int i = 0; i < 16; i += 2) {
        mA = (mA << 1) | (__builtin_bit_cast(uint32_t, C[i])     >> 31);
        mB = (mB << 1) | (__builtin_bit_cast(uint32_t, C[i + 1]) >> 31);
    }
    cnt += __popc(mA) + __popc(mB);
}

__device__ __forceinline__ int swz_g(int g) { return g ^ ((g >> 4) & 3); }

template <int K, int D>
__device__ __forceinline__ void body(const float* __restrict__ x,
                                     const float* __restrict__ wgt,
                                     const float* __restrict__ bias,
                                     const int* __restrict__ list,
                                     int lstart, int valid,
                                     float* __restrict__ out,
                                     short* __restrict__ xs,   // [4][3][CH_ALLOC]
                                     int b) {
    constexpr int H   = (K - 1) / 2;
    constexpr int Q   = 1024 / D;
    constexpr int S   = Q + 16;                    // residue slot stride (gap 16)
    constexpr int RS  = (D <= 4) ? 8 : (D == 8 ? 4 : 2);   // row stride (positions)
    constexpr int NIT = 32;                        // total iterations (all D), even

    const int tid   = threadIdx.x;
    const int lane  = tid & 63;
    const int wave  = tid >> 6;
    const int jbase = (lane >> 5) * 8;             // k-half offset (0 or 8 shorts)
    const int m31   = lane & 31;                   // A row / C-D column index

    // ---- stage: 4 phase-copies, bank-swizzled at 8B-granule level ---------
    for (int idx = tid; idx < 3 * (CH_ALLOC + NPHASE); idx += 256) {
        int c = idx / (CH_ALLOC + NPHASE);
        int P = idx - c * (CH_ALLOC + NPHASE);
        float v = 0.f;
        int y = P - 8;
        if (y >= 0) {
            int r = y / S;
            int q = y - r * S;
            if (r < D && q < Q) v = x[((size_t)b * 3 + c) * 1024 + r + D * q];
        }
        short hv = (short)f32_to_bf16(v);
        #pragma unroll
        for (int pp = 0; pp < NPHASE; ++pp) {
            int ee = P - pp;
            if (ee >= 0 && ee < CH_ALLOC) {
                int phys = (swz_g(ee >> 2) << 2) | (ee & 3);
                xs[pp * PP_STRIDE + c * CH_ALLOC + phys] = hv;
            }
        }
    }

    // ---- per-lane B fragments (single bf16 weights), overlap staging ------
    int i0 = wave * 64 + m31;
    int i1 = i0 + 32;
    int n0 = list[lstart + (i0 < valid ? i0 : valid - 1)];
    int n1 = list[lstart + (i1 < valid ? i1 : valid - 1)];
    short8 whi[2][3];
    #pragma unroll
    for (int t2 = 0; t2 < 2; ++t2) {
        int n = t2 ? n1 : n0;
        #pragma unroll
        for (int c = 0; c < 3; ++c) {
            #pragma unroll
            for (int u = 0; u < 8; ++u) {
                int j = jbase + u;
                float wv = (j < 11) ? wgt[n * 33 + c * 11 + j] : 0.f;
                whi[t2][c][u] = (short)f32_to_bf16(wv);
            }
        }
    }
    float bv0 = bias[n0], bv1 = bias[n1];

    floatx16 BT0, BT1;                             // persistent bias seed tiles
    #pragma unroll
    for (int i = 0; i < 16; ++i) { BT0[i] = bv0; BT1[i] = bv1; }

    __syncthreads();

    // ---- window-start index for flattened iteration it --------------------
    auto calcF = [&](int it) -> int {
        int ri, p;
        if (D <= 4)      { ri = it >> 3; p = it & 7; }
        else if (D == 8) { ri = it >> 2; p = it & 3; }
        else             { ri = it >> 1; p = it & 1; }
        int q0;
        if (D == 1)      q0 = 8 + ri * 256;
        else if (D == 2) q0 = 8 + (ri >> 1) * S + (ri & 1) * 256;
        else             q0 = 8 + ri * S;
        return q0 + p - H + RS * m31;
    };
    // swizzled 2x b64 frag load (frag = logical shorts [(F&~3)+jbase, +8))
    auto loadfrag = [&](int F, short8& A0, short8& A1, short8& A2) {
        int g0 = (F >> 2) + (jbase >> 2);
        int s0 = swz_g(g0) << 2;
        int s1 = swz_g(g0 + 1) << 2;
        const short* bp = xs + (F & 3) * PP_STRIDE;
        short4v l0 = *reinterpret_cast<const short4v*>(bp + s0);
        short4v h0 = *reinterpret_cast<const short4v*>(bp + s1);
        short4v l1 = *reinterpret_cast<const short4v*>(bp + CH_ALLOC + s0);
        short4v h1 = *reinterpret_cast<const short4v*>(bp + CH_ALLOC + s1);
        short4v l2 = *reinterpret_cast<const short4v*>(bp + 2 * CH_ALLOC + s0);
        short4v h2 = *reinterpret_cast<const short4v*>(bp + 2 * CH_ALLOC + s1);
        A0 = __builtin_shufflevector(l0, h0, 0, 1, 2, 3, 4, 5, 6, 7);
        A1 = __builtin_shufflevector(l1, h1, 0, 1, 2, 3, 4, 5, 6, 7);
        A2 = __builtin_shufflevector(l2, h2, 0, 1, 2, 3, 4, 5, 6, 7);
    };

    // ---- main loop: manual x2 unroll, two persistent frag sets ------------
    float mx0 = -3.402823466e38f, mx1 = -3.402823466e38f;
    int cnt0 = 0, cnt1 = 0;                        // negative counts

    short8 a0, a1, a2, b0, b1, b2;
    loadfrag(calcF(0), a0, a1, a2);
    loadfrag(calcF(1), b0, b1, b2);

    #pragma unroll 1
    for (int it = 0; it < NIT; it += 2) {
        int itA = (it + 2 < NIT) ? it + 2 : NIT - 1;   // clamp (redundant reload)
        int itB = (it + 3 < NIT) ? it + 3 : NIT - 1;

        // ---- iteration it (frag set A) ----
        floatx16 C0, C1;
        C0 = __builtin_amdgcn_mfma_f32_32x32x16_bf16(a0, whi[0][0], BT0, 0, 0, 0);
        C0 = __builtin_amdgcn_mfma_f32_32x32x16_bf16(a1, whi[0][1], C0, 0, 0, 0);
        C0 = __builtin_amdgcn_mfma_f32_32x32x16_bf16(a2, whi[0][2], C0, 0, 0, 0);
        C1 = __builtin_amdgcn_mfma_f32_32x32x16_bf16(a0, whi[1][0], BT1, 0, 0, 0);
        C1 = __builtin_amdgcn_mfma_f32_32x32x16_bf16(a1, whi[1][1], C1, 0, 0, 0);
        C1 = __builtin_amdgcn_mfma_f32_32x32x16_bf16(a2, whi[1][2], C1, 0, 0, 0);
        loadfrag(calcF(itA), a0, a1, a2);           // set A free -> prefetch it+2
        stat16(C0, mx0, cnt0);
        stat16(C1, mx1, cnt1);

        // ---- iteration it+1 (frag set B) ----
        floatx16 D0, D1;
        D0 = __builtin_amdgcn_mfma_f32_32x32x16_bf16(b0, whi[0][0], BT0, 0, 0, 0);
        D0 = __builtin_amdgcn_mfma_f32_32x32x16_bf16(b1, whi[0][1], D0, 0, 0, 0);
        D0 = __builtin_amdgcn_mfma_f32_32x32x16_bf16(b2, whi[0][2], D0, 0, 0, 0);
        D1 = __builtin_amdgcn_mfma_f32_32x32x16_bf16(b0, whi[1][0], BT1, 0, 0, 0);
        D1 = __builtin_amdgcn_mfma_f32_32x32x16_bf16(b1, whi[1][1], D1, 0, 0, 0);
        D1 = __builtin_amdgcn_mfma_f32_32x32x16_bf16(b2, whi[1][2], D1, 0, 0, 0);
        loadfrag(calcF(itB), b0, b1, b2);           // set B free -> prefetch it+3
        stat16(D0, mx0, cnt0);
        stat16(D1, mx1, cnt1);
    }

    // ---- merge complementary row halves across the (L, L^32) lane pair ----
    mx0  = fmaxf(mx0, __shfl_xor(mx0, 32));
    mx1  = fmaxf(mx1, __shfl_xor(mx1, 32));
    cnt0 += __shfl_xor(cnt0, 32);
    cnt1 += __shfl_xor(cnt1, 32);

    if (lane < 32) {
        float2* ob = reinterpret_cast<float2*>(out + (size_t)b * (2 * N_KERNELS));
        ob[n0] = make_float2(mx0, (float)(1024 - cnt0) * (1.0f / 1024.0f));
        ob[n1] = make_float2(mx1, (float)(1024 - cnt1) * (1.0f / 1024.0f));
    }
}

__global__ __launch_bounds__(256, 4)
void rocket_main(const float* __restrict__ x, const float* __restrict__ wgt,
                 const float* __restrict__ bias, const int* __restrict__ list,
                 const int* __restrict__ sched, float* __restrict__ out) {
    __shared__ __align__(16) short xs[NPHASE * PP_STRIDE];   // 31.5 KB
    int4 e = reinterpret_cast<const int4*>(sched)[blockIdx.x];
    if (e.w == 0) return;                                // dead chunk — uniform exit
    int b = blockIdx.y;
    int kc = e.x, ld2 = e.y, lstart = e.z, valid = e.w;
    switch (kc * 8 + ld2) {
        case 7*8+0:  body<7, 1 >(x, wgt, bias, list, lstart, valid, out, xs, b); break;
        case 7*8+1:  body<7, 2 >(x, wgt, bias, list, lstart, valid, out, xs, b); break;
        case 7*8+2:  body<7, 4 >(x, wgt, bias, list, lstart, valid, out, xs, b); break;
        case 7*8+3:  body<7, 8 >(x, wgt, bias, list, lstart, valid, out, xs, b); break;
        case 7*8+4:  body<7, 16>(x, wgt, bias, list, lstart, valid, out, xs, b); break;
        case 9*8+0:  body<9, 1 >(x, wgt, bias, list, lstart, valid, out, xs, b); break;
        case 9*8+1:  body<9, 2 >(x, wgt, bias, list, lstart, valid, out, xs, b); break;
        case 9*8+2:  body<9, 4 >(x, wgt, bias, list, lstart, valid, out, xs, b); break;
        case 9*8+3:  body<9, 8 >(x, wgt, bias, list, lstart, valid, out, xs, b); break;
        case 9*8+4:  body<9, 16>(x, wgt, bias, list, lstart, valid, out, xs, b); break;
        case 11*8+0: body<11,1 >(x, wgt, bias, list, lstart, valid, out, xs, b); break;
        case 11*8+1: body<11,2 >(x, wgt, bias, list, lstart, valid, out, xs, b); break;
        case 11*8+2: body<11,4 >(x, wgt, bias, list, lstart, valid, out, xs, b); break;
        case 11*8+3: body<11,8 >(x, wgt, bias, list, lstart, valid, out, xs, b); break;
        default:     body<11,16>(x, wgt, bias, list, lstart, valid, out, xs, b); break;
    }
}

extern "C" void kernel_launch(void* const* d_in, const int* in_sizes, int n_in,
                              void* d_out, int out_size, void* d_ws, size_t ws_size,
                              hipStream_t stream) {
    const float* x   = (const float*)d_in[0];
    const float* w   = (const float*)d_in[1];
    const float* b   = (const float*)d_in[2];
    float* out = (float*)d_out;

    static SetupTables T;       // host-side, computed once (input-independent)

    int* wsi  = (int*)d_ws;
    int* list = wsi;            // 10000 ints
    int* schd = wsi + 10240;    // NCHUNK*4 ints (byte offset 40960, 16B aligned)

    hipMemcpyAsync(d_ws, T.buf, sizeof(T.buf), hipMemcpyHostToDevice, stream);
    hipLaunchKernelGGL(rocket_main,  dim3(NCHUNK, 64), dim3(256), 0, stream,
                       x, w, b, list, schd, out);
}

// Round 3
// 148.387 us; speedup vs baseline: 4.5420x; 1.2564x over previous
//
#include <hip/hip_runtime.h>
#include <stdint.h>

#define N_KERNELS 10000
#define NCHUNK 56            // >= sum_g ceil(size_g/256) worst case
#define CH_ALLOC 1312        // shorts per (copy,channel); mult of 4 (8B granules)
#define PP_STRIDE (3 * CH_ALLOC)
#define NPHASE 4

typedef unsigned __int128 u128;
typedef __attribute__((ext_vector_type(4)))  short short4v;
typedef __attribute__((ext_vector_type(8)))  short short8;
typedef __attribute__((ext_vector_type(16))) float floatx16;

// ---------------------------------------------------------------------------
// R14: setup moved to COMPILE TIME. numpy default_rng(0)'s k/d draws are
// seed-fixed, input-independent; R13's host+memcpyAsync variant showed the
// pageable H2D memcpy node costs ~79us/replay (same as the old setup
// dispatch). constexpr-evaluate the (R1-R10 verified) PCG64/SeedSequence
// algorithm and embed list/sched as a __constant__ global in the code
// object: uploaded at module load, zero per-replay cost.
// Two top-level constexpr initializers keep each under clang's 1M-step cap.
// ---------------------------------------------------------------------------
struct KDraws { uint8_t k[N_KERNELS]; uint8_t d[N_KERNELS]; };

constexpr KDraws make_kd() {
    KDraws kd{};
    const u128 MULT = (((u128)0x2360ED051FC65DA4ULL) << 64) | 0x4385DF649FCCF645ULL;

    // ---- SeedSequence(0) -> PCG64 state (verified vs numpy) --------------
    uint32_t hc = 0x43b0d7e5u;                    // INIT_A
    uint32_t pool[4] = {};
    for (int i = 0; i < 4; i++) {
        uint32_t v = 0u;
        v ^= hc; hc *= 0x931e8875u;               // MULT_A
        v *= hc; v ^= v >> 16;
        pool[i] = v;
    }
    for (int s = 0; s < 4; s++)
        for (int dd = 0; dd < 4; dd++)
            if (s != dd) {
                uint32_t hv = pool[s];
                hv ^= hc; hc *= 0x931e8875u;
                hv *= hc; hv ^= hv >> 16;
                uint32_t rr = 0xca01f9ddu * pool[dd] - 0x4973f715u * hv;
                rr ^= rr >> 16;
                pool[dd] = rr;
            }
    uint32_t st[8] = {};
    uint32_t hcb = 0x8b51f9ddu;                   // INIT_B
    for (int i = 0; i < 8; i++) {
        uint32_t dv = pool[i & 3];
        dv ^= hcb; hcb *= 0x58f38dedu;            // MULT_B
        dv *= hcb; dv ^= dv >> 16;
        st[i] = dv;
    }
    uint64_t w0 = (uint64_t)st[0] | ((uint64_t)st[1] << 32);
    uint64_t w1 = (uint64_t)st[2] | ((uint64_t)st[3] << 32);
    uint64_t w2 = (uint64_t)st[4] | ((uint64_t)st[5] << 32);
    uint64_t w3 = (uint64_t)st[6] | ((uint64_t)st[7] << 32);
    u128 initstate = (((u128)w0) << 64) | w1;
    u128 initseq   = (((u128)w2) << 64) | w3;

    u128 inc   = (initseq << 1) | 1;
    u128 state = 0;
    state = state * MULT + inc;
    state += initstate;
    state = state * MULT + inc;

    // ---- 10000 next64 -> 20000 u32 draws (low word first) ----------------
    u128 s = state;
    for (int t = 0; t < 10000; ++t) {
        s = s * MULT + inc;
        uint64_t hi = (uint64_t)(s >> 64), lo = (uint64_t)s;
        unsigned rot = (unsigned)(hi >> 58);
        uint64_t v = hi ^ lo;
        uint64_t o = (v >> rot) | (v << ((64u - rot) & 63u));
        uint32_t d0 = (uint32_t)o;
        uint32_t d1 = (uint32_t)(o >> 32);
        int i0 = 2 * t, i1 = 2 * t + 1;
        if (i0 < 10000) kd.k[i0] = (uint8_t)(((uint64_t)d0 * 3u) >> 32);
        else            kd.d[i0 - 10000] = (uint8_t)(((uint64_t)d0 * 5u) >> 32);
        if (i1 < 10000) kd.k[i1] = (uint8_t)(((uint64_t)d1 * 3u) >> 32);
        else            kd.d[i1 - 10000] = (uint8_t)(((uint64_t)d1 * 5u) >> 32);
    }
    return kd;
}

constexpr KDraws kdr = make_kd();

struct Tables {
    alignas(16) int sched[4 * NCHUNK];   // int4{k, d_idx, list_start, valid}
    int list[N_KERNELS];
};

constexpr Tables make_tables(const KDraws& kd) {
    Tables T{};
    int cnt[15] = {}, off[15] = {}, cur[15] = {};
    for (int i = 0; i < 10000; ++i) cnt[(int)kd.k[i] * 5 + (int)kd.d[i]]++;
    int o = 0;
    for (int g = 0; g < 15; ++g) { off[g] = o; cur[g] = o; o += cnt[g]; }
    for (int i = 0; i < 10000; ++i) {
        int g = (int)kd.k[i] * 5 + (int)kd.d[i];
        T.list[cur[g]++] = i;
    }
    const int kv[3] = {7, 9, 11};
    int ci = 0;
    for (int g = 0; g < 15; ++g) {
        int sz = cnt[g];
        for (int s2 = 0; s2 < sz; s2 += 256) {
            T.sched[4 * ci + 0] = kv[g / 5];
            T.sched[4 * ci + 1] = g % 5;
            T.sched[4 * ci + 2] = off[g] + s2;
            T.sched[4 * ci + 3] = (sz - s2 < 256) ? (sz - s2) : 256;
            ci++;
        }
    }
    for (; ci < NCHUNK; ci++) {
        T.sched[4 * ci + 0] = 0; T.sched[4 * ci + 1] = 0;
        T.sched[4 * ci + 2] = 0; T.sched[4 * ci + 3] = 0;
    }
    return T;
}

__constant__ Tables g_T = make_tables(kdr);

// ---------------------------------------------------------------------------
// Main: bf16 MFMA Toeplitz GEMM (R6 coverage structure, verified correct).
// R11: manual x2 unroll of the position loop, two persistent frag sets.
// R12 POST-MORTEM: __launch_bounds__(256,5) capped VGPRs below the kernel's
// need -> scratch spills (FETCH 5.4MB -> 1.2GB, 6x slowdown). KEEP (256,4).
// ---------------------------------------------------------------------------
__device__ __forceinline__ uint16_t f32_to_bf16(float v) {
    uint32_t u = __builtin_bit_cast(uint32_t, v);
    return (uint16_t)((u + 0x7FFFu + ((u >> 16) & 1u)) >> 16);
}

__device__ __forceinline__ void stat16(const floatx16& C, float& mx, int& cnt) {
    float g0 = fmaxf(fmaxf(C[0],  C[1]),  C[2]);
    float g1 = fmaxf(fmaxf(C[3],  C[4]),  C[5]);
    float g2 = fmaxf(fmaxf(C[6],  C[7]),  C[8]);
    float g3 = fmaxf(fmaxf(C[9],  C[10]), C[11]);
    float g4 = fmaxf(fmaxf(C[12], C[13]), C[14]);
    float h0 = fmaxf(fmaxf(g0, g1), g2);
    float h1 = fmaxf(fmaxf(g3, g4), C[15]);
    mx = fmaxf(mx, fmaxf(h0, h1));
    uint32_t mA = 0, mB = 0;
    #pragma unroll
    for (int i = 0; i < 16; i += 2) {
        mA = (mA << 1) | (__builtin_bit_cast(uint32_t, C[i])     >> 31);
        mB = (mB << 1) | (__builtin_bit_cast(uint32_t, C[i + 1]) >> 31);
    }
    cnt += __popc(mA) + __popc(mB);
}

__device__ __forceinline__ int swz_g(int g) { return g ^ ((g >> 4) & 3); }

template <int K, int D>
__device__ __forceinline__ void body(const float* __restrict__ x,
                                     const float* __restrict__ wgt,
                                     const float* __restrict__ bias,
                                     int lstart, int valid,
                                     float* __restrict__ out,
                                     short* __restrict__ xs,   // [4][3][CH_ALLOC]
                                     int b) {
    constexpr int H   = (K - 1) / 2;
    constexpr int Q   = 1024 / D;
    constexpr int S   = Q + 16;                    // residue slot stride (gap 16)
    constexpr int RS  = (D <= 4) ? 8 : (D == 8 ? 4 : 2);   // row stride (positions)
    constexpr int NIT = 32;                        // total iterations (all D), even

    const int tid   = threadIdx.x;
    const int lane  = tid & 63;
    const int wave  = tid >> 6;
    const int jbase = (lane >> 5) * 8;             // k-half offset (0 or 8 shorts)
    const int m31   = lane & 31;                   // A row / C-D column index

    // ---- stage: 4 phase-copies, bank-swizzled at 8B-granule level ---------
    for (int idx = tid; idx < 3 * (CH_ALLOC + NPHASE); idx += 256) {
        int c = idx / (CH_ALLOC + NPHASE);
        int P = idx - c * (CH_ALLOC + NPHASE);
        float v = 0.f;
        int y = P - 8;
        if (y >= 0) {
            int r = y / S;
            int q = y - r * S;
            if (r < D && q < Q) v = x[((size_t)b * 3 + c) * 1024 + r + D * q];
        }
        short hv = (short)f32_to_bf16(v);
        #pragma unroll
        for (int pp = 0; pp < NPHASE; ++pp) {
            int ee = P - pp;
            if (ee >= 0 && ee < CH_ALLOC) {
                int phys = (swz_g(ee >> 2) << 2) | (ee & 3);
                xs[pp * PP_STRIDE + c * CH_ALLOC + phys] = hv;
            }
        }
    }

    // ---- per-lane B fragments (single bf16 weights), overlap staging ------
    int i0 = wave * 64 + m31;
    int i1 = i0 + 32;
    int n0 = g_T.list[lstart + (i0 < valid ? i0 : valid - 1)];
    int n1 = g_T.list[lstart + (i1 < valid ? i1 : valid - 1)];
    short8 whi[2][3];
    #pragma unroll
    for (int t2 = 0; t2 < 2; ++t2) {
        int n = t2 ? n1 : n0;
        #pragma unroll
        for (int c = 0; c < 3; ++c) {
            #pragma unroll
            for (int u = 0; u < 8; ++u) {
                int j = jbase + u;
                float wv = (j < 11) ? wgt[n * 33 + c * 11 + j] : 0.f;
                whi[t2][c][u] = (short)f32_to_bf16(wv);
            }
        }
    }
    float bv0 = bias[n0], bv1 = bias[n1];

    floatx16 BT0, BT1;                             // persistent bias seed tiles
    #pragma unroll
    for (int i = 0; i < 16; ++i) { BT0[i] = bv0; BT1[i] = bv1; }

    __syncthreads();

    // ---- window-start index for flattened iteration it --------------------
    auto calcF = [&](int it) -> int {
        int ri, p;
        if (D <= 4)      { ri = it >> 3; p = it & 7; }
        else if (D == 8) { ri = it >> 2; p = it & 3; }
        else             { ri = it >> 1; p = it & 1; }
        int q0;
        if (D == 1)      q0 = 8 + ri * 256;
        else if (D == 2) q0 = 8 + (ri >> 1) * S + (ri & 1) * 256;
        else             q0 = 8 + ri * S;
        return q0 + p - H + RS * m31;
    };
    // swizzled 2x b64 frag load (frag = logical shorts [(F&~3)+jbase, +8))
    auto loadfrag = [&](int F, short8& A0, short8& A1, short8& A2) {
        int g0 = (F >> 2) + (jbase >> 2);
        int s0 = swz_g(g0) << 2;
        int s1 = swz_g(g0 + 1) << 2;
        const short* bp = xs + (F & 3) * PP_STRIDE;
        short4v l0 = *reinterpret_cast<const short4v*>(bp + s0);
        short4v h0 = *reinterpret_cast<const short4v*>(bp + s1);
        short4v l1 = *reinterpret_cast<const short4v*>(bp + CH_ALLOC + s0);
        short4v h1 = *reinterpret_cast<const short4v*>(bp + CH_ALLOC + s1);
        short4v l2 = *reinterpret_cast<const short4v*>(bp + 2 * CH_ALLOC + s0);
        short4v h2 = *reinterpret_cast<const short4v*>(bp + 2 * CH_ALLOC + s1);
        A0 = __builtin_shufflevector(l0, h0, 0, 1, 2, 3, 4, 5, 6, 7);
        A1 = __builtin_shufflevector(l1, h1, 0, 1, 2, 3, 4, 5, 6, 7);
        A2 = __builtin_shufflevector(l2, h2, 0, 1, 2, 3, 4, 5, 6, 7);
    };

    // ---- main loop: manual x2 unroll, two persistent frag sets ------------
    float mx0 = -3.402823466e38f, mx1 = -3.402823466e38f;
    int cnt0 = 0, cnt1 = 0;                        // negative counts

    short8 a0, a1, a2, b0, b1, b2;
    loadfrag(calcF(0), a0, a1, a2);
    loadfrag(calcF(1), b0, b1, b2);

    #pragma unroll 1
    for (int it = 0; it < NIT; it += 2) {
        int itA = (it + 2 < NIT) ? it + 2 : NIT - 1;   // clamp (redundant reload)
        int itB = (it + 3 < NIT) ? it + 3 : NIT - 1;

        // ---- iteration it (frag set A) ----
        floatx16 C0, C1;
        C0 = __builtin_amdgcn_mfma_f32_32x32x16_bf16(a0, whi[0][0], BT0, 0, 0, 0);
        C0 = __builtin_amdgcn_mfma_f32_32x32x16_bf16(a1, whi[0][1], C0, 0, 0, 0);
        C0 = __builtin_amdgcn_mfma_f32_32x32x16_bf16(a2, whi[0][2], C0, 0, 0, 0);
        C1 = __builtin_amdgcn_mfma_f32_32x32x16_bf16(a0, whi[1][0], BT1, 0, 0, 0);
        C1 = __builtin_amdgcn_mfma_f32_32x32x16_bf16(a1, whi[1][1], C1, 0, 0, 0);
        C1 = __builtin_amdgcn_mfma_f32_32x32x16_bf16(a2, whi[1][2], C1, 0, 0, 0);
        loadfrag(calcF(itA), a0, a1, a2);           // set A free -> prefetch it+2
        stat16(C0, mx0, cnt0);
        stat16(C1, mx1, cnt1);

        // ---- iteration it+1 (frag set B) ----
        floatx16 D0, D1;
        D0 = __builtin_amdgcn_mfma_f32_32x32x16_bf16(b0, whi[0][0], BT0, 0, 0, 0);
        D0 = __builtin_amdgcn_mfma_f32_32x32x16_bf16(b1, whi[0][1], D0, 0, 0, 0);
        D0 = __builtin_amdgcn_mfma_f32_32x32x16_bf16(b2, whi[0][2], D0, 0, 0, 0);
        D1 = __builtin_amdgcn_mfma_f32_32x32x16_bf16(b0, whi[1][0], BT1, 0, 0, 0);
        D1 = __builtin_amdgcn_mfma_f32_32x32x16_bf16(b1, whi[1][1], D1, 0, 0, 0);
        D1 = __builtin_amdgcn_mfma_f32_32x32x16_bf16(b2, whi[1][2], D1, 0, 0, 0);
        loadfrag(calcF(itB), b0, b1, b2);           // set B free -> prefetch it+3
        stat16(D0, mx0, cnt0);
        stat16(D1, mx1, cnt1);
    }

    // ---- merge complementary row halves across the (L, L^32) lane pair ----
    mx0  = fmaxf(mx0, __shfl_xor(mx0, 32));
    mx1  = fmaxf(mx1, __shfl_xor(mx1, 32));
    cnt0 += __shfl_xor(cnt0, 32);
    cnt1 += __shfl_xor(cnt1, 32);

    if (lane < 32) {
        float2* ob = reinterpret_cast<float2*>(out + (size_t)b * (2 * N_KERNELS));
        ob[n0] = make_float2(mx0, (float)(1024 - cnt0) * (1.0f / 1024.0f));
        ob[n1] = make_float2(mx1, (float)(1024 - cnt1) * (1.0f / 1024.0f));
    }
}

__global__ __launch_bounds__(256, 4)
void rocket_main(const float* __restrict__ x, const float* __restrict__ wgt,
                 const float* __restrict__ bias, float* __restrict__ out) {
    __shared__ __align__(16) short xs[NPHASE * PP_STRIDE];   // 31.5 KB
    int kc     = g_T.sched[4 * blockIdx.x + 0];
    int ld2    = g_T.sched[4 * blockIdx.x + 1];
    int lstart = g_T.sched[4 * blockIdx.x + 2];
    int valid  = g_T.sched[4 * blockIdx.x + 3];
    if (valid == 0) return;                              // dead chunk — uniform exit
    int b = blockIdx.y;
    switch (kc * 8 + ld2) {
        case 7*8+0:  body<7, 1 >(x, wgt, bias, lstart, valid, out, xs, b); break;
        case 7*8+1:  body<7, 2 >(x, wgt, bias, lstart, valid, out, xs, b); break;
        case 7*8+2:  body<7, 4 >(x, wgt, bias, lstart, valid, out, xs, b); break;
        case 7*8+3:  body<7, 8 >(x, wgt, bias, lstart, valid, out, xs, b); break;
        case 7*8+4:  body<7, 16>(x, wgt, bias, lstart, valid, out, xs, b); break;
        case 9*8+0:  body<9, 1 >(x, wgt, bias, lstart, valid, out, xs, b); break;
        case 9*8+1:  body<9, 2 >(x, wgt, bias, lstart, valid, out, xs, b); break;
        case 9*8+2:  body<9, 4 >(x, wgt, bias, lstart, valid, out, xs, b); break;
        case 9*8+3:  body<9, 8 >(x, wgt, bias, lstart, valid, out, xs, b); break;
        case 9*8+4:  body<9, 16>(x, wgt, bias, lstart, valid, out, xs, b); break;
        case 11*8+0: body<11,1 >(x, wgt, bias, lstart, valid, out, xs, b); break;
        case 11*8+1: body<11,2 >(x, wgt, bias, lstart, valid, out, xs, b); break;
        case 11*8+2: body<11,4 >(x, wgt, bias, lstart, valid, out, xs, b); break;
        case 11*8+3: body<11,8 >(x, wgt, bias, lstart, valid, out, xs, b); break;
        default:     body<11,16>(x, wgt, bias, lstart, valid, out, xs, b); break;
    }
}

extern "C" void kernel_launch(void* const* d_in, const int* in_sizes, int n_in,
                              void* d_out, int out_size, void* d_ws, size_t ws_size,
                              hipStream_t stream) {
    const float* x   = (const float*)d_in[0];
    const float* w   = (const float*)d_in[1];
    const float* b   = (const float*)d_in[2];
    float* out = (float*)d_out;
    (void)d_ws; (void)ws_size;

    hipLaunchKernelGGL(rocket_main, dim3(NCHUNK, 64), dim3(256), 0, stream,
                       x, w, b, out);
}

// Round 4
// 143.094 us; speedup vs baseline: 4.7100x; 1.0370x over previous
//
#include <hip/hip_runtime.h>
#include <stdint.h>

#define N_KERNELS 10000
#define NCHUNK 56            // >= sum_g ceil(size_g/256) worst case
#define CH_ALLOC 1312        // shorts per (copy,channel); mult of 4 (8B granules)
#define PP_STRIDE (3 * CH_ALLOC)
#define NPHASE 4

typedef unsigned __int128 u128;
typedef __attribute__((ext_vector_type(4)))  short short4v;
typedef __attribute__((ext_vector_type(8)))  short short8;
typedef __attribute__((ext_vector_type(16))) float floatx16;

// ---------------------------------------------------------------------------
// R14: setup at COMPILE TIME — numpy default_rng(0)'s k/d draws are seed-
// fixed; constexpr PCG64/SeedSequence (verified R1-R10) embeds list/sched as
// a __constant__ global: uploaded at module load, zero per-replay cost.
// ---------------------------------------------------------------------------
struct KDraws { uint8_t k[N_KERNELS]; uint8_t d[N_KERNELS]; };

constexpr KDraws make_kd() {
    KDraws kd{};
    const u128 MULT = (((u128)0x2360ED051FC65DA4ULL) << 64) | 0x4385DF649FCCF645ULL;

    uint32_t hc = 0x43b0d7e5u;                    // INIT_A
    uint32_t pool[4] = {};
    for (int i = 0; i < 4; i++) {
        uint32_t v = 0u;
        v ^= hc; hc *= 0x931e8875u;               // MULT_A
        v *= hc; v ^= v >> 16;
        pool[i] = v;
    }
    for (int s = 0; s < 4; s++)
        for (int dd = 0; dd < 4; dd++)
            if (s != dd) {
                uint32_t hv = pool[s];
                hv ^= hc; hc *= 0x931e8875u;
                hv *= hc; hv ^= hv >> 16;
                uint32_t rr = 0xca01f9ddu * pool[dd] - 0x4973f715u * hv;
                rr ^= rr >> 16;
                pool[dd] = rr;
            }
    uint32_t st[8] = {};
    uint32_t hcb = 0x8b51f9ddu;                   // INIT_B
    for (int i = 0; i < 8; i++) {
        uint32_t dv = pool[i & 3];
        dv ^= hcb; hcb *= 0x58f38dedu;            // MULT_B
        dv *= hcb; dv ^= dv >> 16;
        st[i] = dv;
    }
    uint64_t w0 = (uint64_t)st[0] | ((uint64_t)st[1] << 32);
    uint64_t w1 = (uint64_t)st[2] | ((uint64_t)st[3] << 32);
    uint64_t w2 = (uint64_t)st[4] | ((uint64_t)st[5] << 32);
    uint64_t w3 = (uint64_t)st[6] | ((uint64_t)st[7] << 32);
    u128 initstate = (((u128)w0) << 64) | w1;
    u128 initseq   = (((u128)w2) << 64) | w3;

    u128 inc   = (initseq << 1) | 1;
    u128 state = 0;
    state = state * MULT + inc;
    state += initstate;
    state = state * MULT + inc;

    u128 s = state;
    for (int t = 0; t < 10000; ++t) {
        s = s * MULT + inc;
        uint64_t hi = (uint64_t)(s >> 64), lo = (uint64_t)s;
        unsigned rot = (unsigned)(hi >> 58);
        uint64_t v = hi ^ lo;
        uint64_t o = (v >> rot) | (v << ((64u - rot) & 63u));
        uint32_t d0 = (uint32_t)o;
        uint32_t d1 = (uint32_t)(o >> 32);
        int i0 = 2 * t, i1 = 2 * t + 1;
        if (i0 < 10000) kd.k[i0] = (uint8_t)(((uint64_t)d0 * 3u) >> 32);
        else            kd.d[i0 - 10000] = (uint8_t)(((uint64_t)d0 * 5u) >> 32);
        if (i1 < 10000) kd.k[i1] = (uint8_t)(((uint64_t)d1 * 3u) >> 32);
        else            kd.d[i1 - 10000] = (uint8_t)(((uint64_t)d1 * 5u) >> 32);
    }
    return kd;
}

constexpr KDraws kdr = make_kd();

struct Tables {
    alignas(16) int sched[4 * NCHUNK];   // int4{k, d_idx, list_start, valid}
    int list[N_KERNELS];
};

constexpr Tables make_tables(const KDraws& kd) {
    Tables T{};
    int cnt[15] = {}, off[15] = {}, cur[15] = {};
    for (int i = 0; i < 10000; ++i) cnt[(int)kd.k[i] * 5 + (int)kd.d[i]]++;
    int o = 0;
    for (int g = 0; g < 15; ++g) { off[g] = o; cur[g] = o; o += cnt[g]; }
    for (int i = 0; i < 10000; ++i) {
        int g = (int)kd.k[i] * 5 + (int)kd.d[i];
        T.list[cur[g]++] = i;
    }
    const int kv[3] = {7, 9, 11};
    int ci = 0;
    for (int g = 0; g < 15; ++g) {
        int sz = cnt[g];
        for (int s2 = 0; s2 < sz; s2 += 256) {
            T.sched[4 * ci + 0] = kv[g / 5];
            T.sched[4 * ci + 1] = g % 5;
            T.sched[4 * ci + 2] = off[g] + s2;
            T.sched[4 * ci + 3] = (sz - s2 < 256) ? (sz - s2) : 256;
            ci++;
        }
    }
    for (; ci < NCHUNK; ci++) {
        T.sched[4 * ci + 0] = 0; T.sched[4 * ci + 1] = 0;
        T.sched[4 * ci + 2] = 0; T.sched[4 * ci + 3] = 0;
    }
    return T;
}

__constant__ Tables g_T = make_tables(kdr);

// ---------------------------------------------------------------------------
// Main: bf16 MFMA Toeplitz GEMM (R6 coverage structure, verified correct).
// R11: manual x2 unroll, two persistent frag sets.
// R12 POST-MORTEM: (256,5) -> VGPR cap 48 -> scratch spill 1.2GB. KEEP (256,4).
// R15: stat16 count path rewritten — shift-mask+popc (4 inst/2elem + 2 popc)
// replaced by arithmetic sign accumulation: ashr(-1/0) x2 + v_add3_u32
// (3 inst/2elem, no popc). stat16 ~42 -> ~31 VALU inst; stat16 was ~73% of
// VALU work and VALUBusy(61%) >> MfmaUtil(29%) was the critical path.
// cnt now accumulates -(#negatives): ppv = (1024 + cnt)/1024.
// ---------------------------------------------------------------------------
__device__ __forceinline__ uint16_t f32_to_bf16(float v) {
    uint32_t u = __builtin_bit_cast(uint32_t, v);
    return (uint16_t)((u + 0x7FFFu + ((u >> 16) & 1u)) >> 16);
}

__device__ __forceinline__ void stat16(const floatx16& C, float& mx, int& cnt) {
    float g0 = fmaxf(fmaxf(C[0],  C[1]),  C[2]);
    float g1 = fmaxf(fmaxf(C[3],  C[4]),  C[5]);
    float g2 = fmaxf(fmaxf(C[6],  C[7]),  C[8]);
    float g3 = fmaxf(fmaxf(C[9],  C[10]), C[11]);
    float g4 = fmaxf(fmaxf(C[12], C[13]), C[14]);
    float h0 = fmaxf(fmaxf(g0, g1), g2);
    float h1 = fmaxf(fmaxf(g3, g4), C[15]);
    mx = fmaxf(mx, fmaxf(h0, h1));
    #pragma unroll
    for (int i = 0; i < 16; i += 2) {
        int s0 = __builtin_bit_cast(int, C[i])     >> 31;   // -1 if negative
        int s1 = __builtin_bit_cast(int, C[i + 1]) >> 31;
        cnt += s0 + s1;                                     // v_add3_u32
    }
}

__device__ __forceinline__ int swz_g(int g) { return g ^ ((g >> 4) & 3); }

template <int K, int D>
__device__ __forceinline__ void body(const float* __restrict__ x,
                                     const float* __restrict__ wgt,
                                     const float* __restrict__ bias,
                                     int lstart, int valid,
                                     float* __restrict__ out,
                                     short* __restrict__ xs,   // [4][3][CH_ALLOC]
                                     int b) {
    constexpr int H   = (K - 1) / 2;
    constexpr int Q   = 1024 / D;
    constexpr int S   = Q + 16;                    // residue slot stride (gap 16)
    constexpr int RS  = (D <= 4) ? 8 : (D == 8 ? 4 : 2);   // row stride (positions)
    constexpr int NIT = 32;                        // total iterations (all D), even

    const int tid   = threadIdx.x;
    const int lane  = tid & 63;
    const int wave  = tid >> 6;
    const int jbase = (lane >> 5) * 8;             // k-half offset (0 or 8 shorts)
    const int m31   = lane & 31;                   // A row / C-D column index

    // ---- stage: 4 phase-copies, bank-swizzled at 8B-granule level ---------
    for (int idx = tid; idx < 3 * (CH_ALLOC + NPHASE); idx += 256) {
        int c = idx / (CH_ALLOC + NPHASE);
        int P = idx - c * (CH_ALLOC + NPHASE);
        float v = 0.f;
        int y = P - 8;
        if (y >= 0) {
            int r = y / S;
            int q = y - r * S;
            if (r < D && q < Q) v = x[((size_t)b * 3 + c) * 1024 + r + D * q];
        }
        short hv = (short)f32_to_bf16(v);
        #pragma unroll
        for (int pp = 0; pp < NPHASE; ++pp) {
            int ee = P - pp;
            if (ee >= 0 && ee < CH_ALLOC) {
                int phys = (swz_g(ee >> 2) << 2) | (ee & 3);
                xs[pp * PP_STRIDE + c * CH_ALLOC + phys] = hv;
            }
        }
    }

    // ---- per-lane B fragments (single bf16 weights), overlap staging ------
    int i0 = wave * 64 + m31;
    int i1 = i0 + 32;
    int n0 = g_T.list[lstart + (i0 < valid ? i0 : valid - 1)];
    int n1 = g_T.list[lstart + (i1 < valid ? i1 : valid - 1)];
    short8 whi[2][3];
    #pragma unroll
    for (int t2 = 0; t2 < 2; ++t2) {
        int n = t2 ? n1 : n0;
        #pragma unroll
        for (int c = 0; c < 3; ++c) {
            #pragma unroll
            for (int u = 0; u < 8; ++u) {
                int j = jbase + u;
                float wv = (j < 11) ? wgt[n * 33 + c * 11 + j] : 0.f;
                whi[t2][c][u] = (short)f32_to_bf16(wv);
            }
        }
    }
    float bv0 = bias[n0], bv1 = bias[n1];

    floatx16 BT0, BT1;                             // persistent bias seed tiles
    #pragma unroll
    for (int i = 0; i < 16; ++i) { BT0[i] = bv0; BT1[i] = bv1; }

    __syncthreads();

    // ---- window-start index for flattened iteration it --------------------
    auto calcF = [&](int it) -> int {
        int ri, p;
        if (D <= 4)      { ri = it >> 3; p = it & 7; }
        else if (D == 8) { ri = it >> 2; p = it & 3; }
        else             { ri = it >> 1; p = it & 1; }
        int q0;
        if (D == 1)      q0 = 8 + ri * 256;
        else if (D == 2) q0 = 8 + (ri >> 1) * S + (ri & 1) * 256;
        else             q0 = 8 + ri * S;
        return q0 + p - H + RS * m31;
    };
    // swizzled 2x b64 frag load (frag = logical shorts [(F&~3)+jbase, +8))
    auto loadfrag = [&](int F, short8& A0, short8& A1, short8& A2) {
        int g0 = (F >> 2) + (jbase >> 2);
        int s0 = swz_g(g0) << 2;
        int s1 = swz_g(g0 + 1) << 2;
        const short* bp = xs + (F & 3) * PP_STRIDE;
        short4v l0 = *reinterpret_cast<const short4v*>(bp + s0);
        short4v h0 = *reinterpret_cast<const short4v*>(bp + s1);
        short4v l1 = *reinterpret_cast<const short4v*>(bp + CH_ALLOC + s0);
        short4v h1 = *reinterpret_cast<const short4v*>(bp + CH_ALLOC + s1);
        short4v l2 = *reinterpret_cast<const short4v*>(bp + 2 * CH_ALLOC + s0);
        short4v h2 = *reinterpret_cast<const short4v*>(bp + 2 * CH_ALLOC + s1);
        A0 = __builtin_shufflevector(l0, h0, 0, 1, 2, 3, 4, 5, 6, 7);
        A1 = __builtin_shufflevector(l1, h1, 0, 1, 2, 3, 4, 5, 6, 7);
        A2 = __builtin_shufflevector(l2, h2, 0, 1, 2, 3, 4, 5, 6, 7);
    };

    // ---- main loop: manual x2 unroll, two persistent frag sets ------------
    float mx0 = -3.402823466e38f, mx1 = -3.402823466e38f;
    int cnt0 = 0, cnt1 = 0;                        // -(negative counts)

    short8 a0, a1, a2, b0, b1, b2;
    loadfrag(calcF(0), a0, a1, a2);
    loadfrag(calcF(1), b0, b1, b2);

    #pragma unroll 1
    for (int it = 0; it < NIT; it += 2) {
        int itA = (it + 2 < NIT) ? it + 2 : NIT - 1;   // clamp (redundant reload)
        int itB = (it + 3 < NIT) ? it + 3 : NIT - 1;

        // ---- iteration it (frag set A) ----
        floatx16 C0, C1;
        C0 = __builtin_amdgcn_mfma_f32_32x32x16_bf16(a0, whi[0][0], BT0, 0, 0, 0);
        C0 = __builtin_amdgcn_mfma_f32_32x32x16_bf16(a1, whi[0][1], C0, 0, 0, 0);
        C0 = __builtin_amdgcn_mfma_f32_32x32x16_bf16(a2, whi[0][2], C0, 0, 0, 0);
        C1 = __builtin_amdgcn_mfma_f32_32x32x16_bf16(a0, whi[1][0], BT1, 0, 0, 0);
        C1 = __builtin_amdgcn_mfma_f32_32x32x16_bf16(a1, whi[1][1], C1, 0, 0, 0);
        C1 = __builtin_amdgcn_mfma_f32_32x32x16_bf16(a2, whi[1][2], C1, 0, 0, 0);
        loadfrag(calcF(itA), a0, a1, a2);           // set A free -> prefetch it+2
        stat16(C0, mx0, cnt0);
        stat16(C1, mx1, cnt1);

        // ---- iteration it+1 (frag set B) ----
        floatx16 D0, D1;
        D0 = __builtin_amdgcn_mfma_f32_32x32x16_bf16(b0, whi[0][0], BT0, 0, 0, 0);
        D0 = __builtin_amdgcn_mfma_f32_32x32x16_bf16(b1, whi[0][1], D0, 0, 0, 0);
        D0 = __builtin_amdgcn_mfma_f32_32x32x16_bf16(b2, whi[0][2], D0, 0, 0, 0);
        D1 = __builtin_amdgcn_mfma_f32_32x32x16_bf16(b0, whi[1][0], BT1, 0, 0, 0);
        D1 = __builtin_amdgcn_mfma_f32_32x32x16_bf16(b1, whi[1][1], D1, 0, 0, 0);
        D1 = __builtin_amdgcn_mfma_f32_32x32x16_bf16(b2, whi[1][2], D1, 0, 0, 0);
        loadfrag(calcF(itB), b0, b1, b2);           // set B free -> prefetch it+3
        stat16(D0, mx0, cnt0);
        stat16(D1, mx1, cnt1);
    }

    // ---- merge complementary row halves across the (L, L^32) lane pair ----
    mx0  = fmaxf(mx0, __shfl_xor(mx0, 32));
    mx1  = fmaxf(mx1, __shfl_xor(mx1, 32));
    cnt0 += __shfl_xor(cnt0, 32);
    cnt1 += __shfl_xor(cnt1, 32);

    if (lane < 32) {
        float2* ob = reinterpret_cast<float2*>(out + (size_t)b * (2 * N_KERNELS));
        ob[n0] = make_float2(mx0, (float)(1024 + cnt0) * (1.0f / 1024.0f));
        ob[n1] = make_float2(mx1, (float)(1024 + cnt1) * (1.0f / 1024.0f));
    }
}

__global__ __launch_bounds__(256, 4)
void rocket_main(const float* __restrict__ x, const float* __restrict__ wgt,
                 const float* __restrict__ bias, float* __restrict__ out) {
    __shared__ __align__(16) short xs[NPHASE * PP_STRIDE];   // 31.5 KB
    int kc     = g_T.sched[4 * blockIdx.x + 0];
    int ld2    = g_T.sched[4 * blockIdx.x + 1];
    int lstart = g_T.sched[4 * blockIdx.x + 2];
    int valid  = g_T.sched[4 * blockIdx.x + 3];
    if (valid == 0) return;                              // dead chunk — uniform exit
    int b = blockIdx.y;
    switch (kc * 8 + ld2) {
        case 7*8+0:  body<7, 1 >(x, wgt, bias, lstart, valid, out, xs, b); break;
        case 7*8+1:  body<7, 2 >(x, wgt, bias, lstart, valid, out, xs, b); break;
        case 7*8+2:  body<7, 4 >(x, wgt, bias, lstart, valid, out, xs, b); break;
        case 7*8+3:  body<7, 8 >(x, wgt, bias, lstart, valid, out, xs, b); break;
        case 7*8+4:  body<7, 16>(x, wgt, bias, lstart, valid, out, xs, b); break;
        case 9*8+0:  body<9, 1 >(x, wgt, bias, lstart, valid, out, xs, b); break;
        case 9*8+1:  body<9, 2 >(x, wgt, bias, lstart, valid, out, xs, b); break;
        case 9*8+2:  body<9, 4 >(x, wgt, bias, lstart, valid, out, xs, b); break;
        case 9*8+3:  body<9, 8 >(x, wgt, bias, lstart, valid, out, xs, b); break;
        case 9*8+4:  body<9, 16>(x, wgt, bias, lstart, valid, out, xs, b); break;
        case 11*8+0: body<11,1 >(x, wgt, bias, lstart, valid, out, xs, b); break;
        case 11*8+1: body<11,2 >(x, wgt, bias, lstart, valid, out, xs, b); break;
        case 11*8+2: body<11,4 >(x, wgt, bias, lstart, valid, out, xs, b); break;
        case 11*8+3: body<11,8 >(x, wgt, bias, lstart, valid, out, xs, b); break;
        default:     body<11,16>(x, wgt, bias, lstart, valid, out, xs, b); break;
    }
}

extern "C" void kernel_launch(void* const* d_in, const int* in_sizes, int n_in,
                              void* d_out, int out_size, void* d_ws, size_t ws_size,
                              hipStream_t stream) {
    const float* x   = (const float*)d_in[0];
    const float* w   = (const float*)d_in[1];
    const float* b   = (const float*)d_in[2];
    float* out = (float*)d_out;
    (void)d_ws; (void)ws_size;

    hipLaunchKernelGGL(rocket_main, dim3(NCHUNK, 64), dim3(256), 0, stream,
                       x, w, b, out);
}